// Round 7
// baseline (236.475 us; speedup 1.0000x reference)
//
#include <hip/hip_runtime.h>
#include <math.h>

constexpr int KK = 2;
constexpr int HH = 4;
constexpr int NN = 4096;
constexpr int DD = 64;
constexpr int OO = 64;
constexpr int NU = 4000;
constexpr int CC = 2;
constexpr int JSPLIT = 8;
constexpr int JCHUNK = NN / JSPLIT;  // 512
constexpr float LOG2E = 1.44269504088896340736f;

typedef float vf4 __attribute__((ext_vector_type(4)));
typedef float vf2 __attribute__((ext_vector_type(2)));

__device__ __forceinline__ float fexp2(float x) {
#if __has_builtin(__builtin_amdgcn_exp2f)
  return __builtin_amdgcn_exp2f(x);
#else
  return exp2f(x);
#endif
}
__device__ __forceinline__ float frcp(float x) {
#if __has_builtin(__builtin_amdgcn_rcpf)
  return __builtin_amdgcn_rcpf(x);
#else
  return 1.0f / x;
#endif
}
__device__ __forceinline__ float ftanh(float x) {
  float e = fexp2(x * (2.0f * LOG2E));
  return 1.0f - 2.0f * frcp(e + 1.0f);
}

// ---------------------------------------------------------------------------
// Phase 1: per (k,h): hp = h @ w (4096x64 @ 64x64); per node j:
//   src_s[kh][j] = (tanh(hp_j).a_src)*log2e
//   att_d [kh][j] = (tanh(hp_j).a_dst)*log2e
//   att_g0[kh][j] = hp_j . fc_w[0, k*O:], att_g1 likewise  (SoA planes)
// grid (128, K*H), block 256. Thread = 2 rows x 4 o outer-product tile.
// ---------------------------------------------------------------------------
__global__ __launch_bounds__(256) void gat_phase1(
    const float* __restrict__ hsrc, const float* __restrict__ w,
    const float* __restrict__ a_src, const float* __restrict__ a_dst,
    const float* __restrict__ fc_w,
    float* __restrict__ src_s, float* __restrict__ att_d,
    float* __restrict__ att_g0, float* __restrict__ att_g1) {
  const int kh = blockIdx.y;  // 0..7
  const int k = kh >> 2;
  const int i0 = blockIdx.x * 32;
  const int tid = threadIdx.x;

  __shared__ float h_s[DD][36];  // [f][row], 32 rows + pad
  __shared__ float w_s[DD][OO];  // [f][o]

  {
    const vf4* wp = (const vf4*)(w + (size_t)kh * DD * OO);
    vf4* ws4 = (vf4*)w_s;
#pragma unroll
    for (int t = tid; t < DD * OO / 4; t += 256) ws4[t] = wp[t];
  }
#pragma unroll
  for (int t = tid; t < 512; t += 256) {  // 32 rows x 16 vf4
    const int row = t >> 4;
    const int f4 = (t & 15) * 4;
    vf4 v = *(const vf4*)(hsrc + (size_t)(i0 + row) * DD + f4);
    h_s[f4 + 0][row] = v.x;
    h_s[f4 + 1][row] = v.y;
    h_s[f4 + 2][row] = v.z;
    h_s[f4 + 3][row] = v.w;
  }
  __syncthreads();

  const int og = tid & 15;  // o-group: o0 = og*4
  const int rg = tid >> 4;  // row-group 0..15: rows r0, r0+1
  const int o0 = og * 4;
  const int r0 = rg * 2;

  float hp[2][4];
#pragma unroll
  for (int j = 0; j < 2; ++j)
#pragma unroll
    for (int u = 0; u < 4; ++u) hp[j][u] = 0.0f;

#pragma unroll 8
  for (int f = 0; f < DD; ++f) {
    vf2 hv = *(const vf2*)&h_s[f][r0];
    vf4 wv = *(const vf4*)&w_s[f][o0];
    hp[0][0] = fmaf(hv.x, wv.x, hp[0][0]);
    hp[0][1] = fmaf(hv.x, wv.y, hp[0][1]);
    hp[0][2] = fmaf(hv.x, wv.z, hp[0][2]);
    hp[0][3] = fmaf(hv.x, wv.w, hp[0][3]);
    hp[1][0] = fmaf(hv.y, wv.x, hp[1][0]);
    hp[1][1] = fmaf(hv.y, wv.y, hp[1][1]);
    hp[1][2] = fmaf(hv.y, wv.z, hp[1][2]);
    hp[1][3] = fmaf(hv.y, wv.w, hp[1][3]);
  }

  float as[4], ad[4], f0[4], f1[4];
#pragma unroll
  for (int u = 0; u < 4; ++u) {
    as[u] = a_src[kh * OO + o0 + u];
    ad[u] = a_dst[kh * OO + o0 + u];
    f0[u] = fc_w[0 * (KK * OO) + k * OO + o0 + u];
    f1[u] = fc_w[1 * (KK * OO) + k * OO + o0 + u];
  }

#pragma unroll
  for (int j = 0; j < 2; ++j) {
    float sp = 0.0f, dp = 0.0f, g0 = 0.0f, g1 = 0.0f;
#pragma unroll
    for (int u = 0; u < 4; ++u) {
      float v = hp[j][u];
      float t = ftanh(v);
      sp = fmaf(t, as[u], sp);
      dp = fmaf(t, ad[u], dp);
      g0 = fmaf(v, f0[u], g0);
      g1 = fmaf(v, f1[u], g1);
    }
#pragma unroll
    for (int off = 1; off < 16; off <<= 1) {
      sp += __shfl_xor(sp, off, 64);
      dp += __shfl_xor(dp, off, 64);
      g0 += __shfl_xor(g0, off, 64);
      g1 += __shfl_xor(g1, off, 64);
    }
    if (og == 0) {
      const int i = i0 + r0 + j;
      src_s[kh * NN + i] = sp * LOG2E;
      att_d[kh * NN + i] = dp * LOG2E;
      att_g0[kh * NN + i] = g0;
      att_g1[kh * NN + i] = g1;
    }
  }
}

// ---------------------------------------------------------------------------
// Phase 2: partial softmax sums over a 512-j chunk, 32 rows per block.
// grid (NU/32, K*JSPLIT), block 256 = 4 waves. Lane = (jsub<<5) | row.
// Block stages the chunk's att planes (12 x 512 floats = 24 KB) into LDS;
// inner loop per 8-j tile: 1 dense global adj b128 (prefetched 2 deep) +
// 12 broadcast ds_read_b128 + packed-f32 VALU on j-pairs:
//   p = adj * exp2(0.6*s + 0.4*|s|)   [== leaky, exact]; l += p; a_c += p*g_c
// Reduction: butterfly xor 32 (j-subs) + fold pair + LDS combine (4 waves).
// ---------------------------------------------------------------------------
__global__ __launch_bounds__(256) void gat_phase2(
    const float* __restrict__ adj, const float* __restrict__ src_s,
    const float* __restrict__ att_d, const float* __restrict__ att_g0,
    const float* __restrict__ att_g1, float* __restrict__ P) {
  const int k = blockIdx.y >> 3;
  const int chunk = blockIdx.y & 7;
  const int r0 = blockIdx.x * 32;
  const int tid = threadIdx.x;
  const int wave = tid >> 6;
  const int lane = tid & 63;
  const int row = lane & 31;
  const int jsub = lane >> 5;  // 0..1
  const int i = r0 + row;
  const int j0 = chunk * JCHUNK;

  // ---- stage att chunk into LDS: lds_att[v][j], v = plane*4 + h ----
  __shared__ float lds_att[12][JCHUNK];
  {
    const float* planes[3] = {att_d, att_g0, att_g1};
#pragma unroll
    for (int step = 0; step < 6; ++step) {  // 12 * 128 vf4 / 256 thr
      const int fi = step * 256 + tid;
      const int v = fi >> 7;  // 128 vf4 per (plane,h) row
      const int pos = (fi & 127) * 4;
      const int p = v >> 2, h = v & 3;
      vf4 val = *(const vf4*)(planes[p] + (size_t)(k * HH + h) * NN + j0 + pos);
      *(vf4*)&lds_att[v][pos] = val;
    }
  }

  vf2 sreg2[4];
#pragma unroll
  for (int h = 0; h < 4; ++h) {
    float s = src_s[(k * HH + h) * NN + i];
    sreg2[h].x = s;
    sreg2[h].y = s;
  }

  vf2 l2[4], a02[4], a12[4];
#pragma unroll
  for (int h = 0; h < 4; ++h) {
    l2[h] = (vf2)(0.0f);
    a02[h] = (vf2)(0.0f);
    a12[h] = (vf2)(0.0f);
  }

  __syncthreads();

  // 64 tiles of 8 j; wave handles t = wave, wave+4, ... (16 of them)
  const float* arow =
      adj + (size_t)k * NN * NN + (size_t)i * NN + j0 + jsub * 4;
  vf4 apre0 = *(const vf4*)(arow + (wave + 0) * 8);
  vf4 apre1 = *(const vf4*)(arow + (wave + 4) * 8);

#pragma unroll 4
  for (int s = 0; s < 16; ++s) {
    const int t = wave + s * 4;
    const vf4 av = apre0;
    apre0 = apre1;
    if (s < 14) apre1 = *(const vf4*)(arow + (wave + (s + 2) * 4) * 8);
    const int jloc = t * 8 + jsub * 4;
#pragma unroll
    for (int h = 0; h < 4; ++h) {
      vf4 dv = *(const vf4*)&lds_att[0 * 4 + h][jloc];
      vf4 g0v = *(const vf4*)&lds_att[1 * 4 + h][jloc];
      vf4 g1v = *(const vf4*)&lds_att[2 * 4 + h][jloc];
#pragma unroll
      for (int pp = 0; pp < 2; ++pp) {
        vf2 dpair = {dv[2 * pp], dv[2 * pp + 1]};
        vf2 apair = {av[2 * pp], av[2 * pp + 1]};
        vf2 g0p = {g0v[2 * pp], g0v[2 * pp + 1]};
        vf2 g1p = {g1v[2 * pp], g1v[2 * pp + 1]};
        vf2 s2 = sreg2[h] + dpair;          // v_pk_add_f32
        vf2 t6 = s2 * 0.6f;                 // v_pk_mul_f32
        vf2 e;                               // leaky = 0.6s + 0.4|s| (exact)
        e.x = fexp2(fmaf(0.4f, __builtin_fabsf(s2.x), t6.x));
        e.y = fexp2(fmaf(0.4f, __builtin_fabsf(s2.y), t6.y));
        vf2 p2 = apair * e;                 // v_pk_mul_f32
        l2[h] += p2;                         // v_pk_add_f32
        a02[h] = __builtin_elementwise_fma(p2, g0p, a02[h]);  // v_pk_fma_f32
        a12[h] = __builtin_elementwise_fma(p2, g1p, a12[h]);
      }
    }
  }

  // fold: butterfly over jsub (lane bit 5), then pair halves
  float l[4], a0[4], a1[4];
#pragma unroll
  for (int h = 0; h < 4; ++h) {
    vf2 x0 = l2[h], x1 = a02[h], x2 = a12[h];
    x0.x += __shfl_xor(x0.x, 32, 64);
    x0.y += __shfl_xor(x0.y, 32, 64);
    x1.x += __shfl_xor(x1.x, 32, 64);
    x1.y += __shfl_xor(x1.y, 32, 64);
    x2.x += __shfl_xor(x2.x, 32, 64);
    x2.y += __shfl_xor(x2.y, 32, 64);
    l[h] = x0.x + x0.y;
    a0[h] = x1.x + x1.y;
    a1[h] = x2.x + x2.y;
  }

  // cross-wave combine: sred[wave][v][row], v = h*3+c
  __shared__ float sred[4][12][32];
  if (lane < 32) {
#pragma unroll
    for (int h = 0; h < 4; ++h) {
      sred[wave][h * 3 + 0][row] = l[h];
      sred[wave][h * 3 + 1][row] = a0[h];
      sred[wave][h * 3 + 2][row] = a1[h];
    }
  }
  __syncthreads();
#pragma unroll
  for (int idx = tid; idx < 384; idx += 256) {
    const int v = idx >> 5;  // 0..11 = h*3+c
    const int rr = idx & 31;
    float sum =
        sred[0][v][rr] + sred[1][v][rr] + sred[2][v][rr] + sred[3][v][rr];
    const int h = v / 3, c = v % 3;
    // P layout: [k][chunk][h][{l,a0,a1}][i]
    size_t base =
        ((((size_t)(k * JSPLIT + chunk) * HH + h) * 3 + c)) * NU + (r0 + rr);
    P[base] = sum;
  }
}

// ---------------------------------------------------------------------------
// Phase 3: combine chunk partials, divide, mean heads, sum kinds, +bias,
// log_softmax over C=2.
// ---------------------------------------------------------------------------
__global__ __launch_bounds__(256) void gat_phase3(
    const float* __restrict__ P, const float* __restrict__ fc_b,
    float* __restrict__ out) {
  const int i = blockIdx.x * 256 + threadIdx.x;
  if (i >= NU) return;
  float l0 = fc_b[0], l1 = fc_b[1];
#pragma unroll
  for (int k = 0; k < KK; ++k) {
#pragma unroll
    for (int q = 0; q < HH; ++q) {
      float ls = 0.0f, a0 = 0.0f, a1 = 0.0f;
#pragma unroll
      for (int ch = 0; ch < JSPLIT; ++ch) {
        size_t b = (((size_t)(k * JSPLIT + ch) * HH + q) * 3) * NU + i;
        ls += P[b];
        a0 += P[b + NU];
        a1 += P[b + 2 * (size_t)NU];
      }
      float inv = 1.0f / ls;
      l0 = fmaf(0.25f * a0, inv, l0);
      l1 = fmaf(0.25f * a1, inv, l1);
    }
  }
  float m = fmaxf(l0, l1);
  float lse = m + logf(expf(l0 - m) + expf(l1 - m));
  out[i * CC + 0] = l0 - lse;
  out[i * CC + 1] = l1 - lse;
}

extern "C" void kernel_launch(void* const* d_in, const int* in_sizes, int n_in,
                              void* d_out, int out_size, void* d_ws, size_t ws_size,
                              hipStream_t stream) {
  const float* hsrc  = (const float*)d_in[0];  // (1,4096,64)
  const float* hadj  = (const float*)d_in[1];  // (2,1,4096,4096)
  const float* w     = (const float*)d_in[2];  // (2,4,64,64)
  const float* a_src = (const float*)d_in[3];  // (2,4,64,1)
  const float* a_dst = (const float*)d_in[4];  // (2,4,64,1)
  const float* fc_w  = (const float*)d_in[5];  // (2,128)
  const float* fc_b  = (const float*)d_in[6];  // (2,)
  float* out = (float*)d_out;                  // (1,4000,2) fp32

  char* ws = (char*)d_ws;
  float* src_s  = (float*)(ws + 0 * 131072);   // K*H*N floats (128 KB each)
  float* att_d  = (float*)(ws + 1 * 131072);
  float* att_g0 = (float*)(ws + 2 * 131072);
  float* att_g1 = (float*)(ws + 3 * 131072);
  float* P      = (float*)(ws + 4 * 131072);   // K*JSPLIT*H*3*NU = 3 MB

  dim3 g1(NN / 32, KK * HH);
  gat_phase1<<<g1, 256, 0, stream>>>(hsrc, w, a_src, a_dst, fc_w,
                                     src_s, att_d, att_g0, att_g1);
  dim3 g2(NU / 32, KK * JSPLIT);
  gat_phase2<<<g2, 256, 0, stream>>>(hadj, src_s, att_d, att_g0, att_g1, P);
  gat_phase3<<<(NU + 255) / 256, 256, 0, stream>>>(P, fc_b, out);
}

// Round 8
// 225.300 us; speedup vs baseline: 1.0496x; 1.0496x over previous
//
#include <hip/hip_runtime.h>
#include <math.h>

constexpr int KK = 2;
constexpr int HH = 4;
constexpr int NN = 4096;
constexpr int DD = 64;
constexpr int OO = 64;
constexpr int NU = 4000;
constexpr int CC = 2;
constexpr int JSPLIT = 8;
constexpr int JCHUNK = NN / JSPLIT;  // 512
constexpr float LOG2E = 1.44269504088896340736f;

typedef float vf4 __attribute__((ext_vector_type(4)));
typedef float vf2 __attribute__((ext_vector_type(2)));

__device__ __forceinline__ float fexp2(float x) {
#if __has_builtin(__builtin_amdgcn_exp2f)
  return __builtin_amdgcn_exp2f(x);
#else
  return exp2f(x);
#endif
}
__device__ __forceinline__ float frcp(float x) {
#if __has_builtin(__builtin_amdgcn_rcpf)
  return __builtin_amdgcn_rcpf(x);
#else
  return 1.0f / x;
#endif
}
__device__ __forceinline__ float ftanh(float x) {
  float e = fexp2(x * (2.0f * LOG2E));
  return 1.0f - 2.0f * frcp(e + 1.0f);
}

// ---------------------------------------------------------------------------
// Phase 1: per (k,h): hp = h @ w (4096x64 @ 64x64); per node j:
//   src_s[kh][j] = (tanh(hp_j).a_src)*log2e
//   att_d [kh][j] = (tanh(hp_j).a_dst)*log2e
//   att_g0[kh][j] = hp_j . fc_w[0, k*O:], att_g1 likewise  (SoA planes)
// grid (64, K*H), block 256. Thread = 4 rows x 4 o outer-product tile.
// Epilogue: LDS transpose (no cross-lane shuffle chains).
// ---------------------------------------------------------------------------
__global__ __launch_bounds__(256) void gat_phase1(
    const float* __restrict__ hsrc, const float* __restrict__ w,
    const float* __restrict__ a_src, const float* __restrict__ a_dst,
    const float* __restrict__ fc_w,
    float* __restrict__ src_s, float* __restrict__ att_d,
    float* __restrict__ att_g0, float* __restrict__ att_g1) {
  const int kh = blockIdx.y;  // 0..7
  const int k = kh >> 2;
  const int i0 = blockIdx.x * 64;
  const int tid = threadIdx.x;

  __shared__ float h_s[DD][68];
  __shared__ float w_s[DD][OO];
  __shared__ float part[4][64][17];  // [val][row][og], padded

  {
    const vf4* wp = (const vf4*)(w + (size_t)kh * DD * OO);
    vf4* ws4 = (vf4*)w_s;
    for (int t = tid; t < DD * OO / 4; t += 256) ws4[t] = wp[t];
  }
  for (int t = tid; t < 1024; t += 256) {
    const int row = t >> 4;
    const int f4 = (t & 15) * 4;
    vf4 v = *(const vf4*)(hsrc + (size_t)(i0 + row) * DD + f4);
    h_s[f4 + 0][row] = v.x;
    h_s[f4 + 1][row] = v.y;
    h_s[f4 + 2][row] = v.z;
    h_s[f4 + 3][row] = v.w;
  }
  __syncthreads();

  const int og = tid & 15;
  const int rg = tid >> 4;
  const int o0 = og * 4;
  const int r0 = rg * 4;

  float hp[4][4];
#pragma unroll
  for (int j = 0; j < 4; ++j)
#pragma unroll
    for (int u = 0; u < 4; ++u) hp[j][u] = 0.0f;

#pragma unroll 8
  for (int f = 0; f < DD; ++f) {
    vf4 hv = *(const vf4*)&h_s[f][r0];
    vf4 wv = *(const vf4*)&w_s[f][o0];
    hp[0][0] = fmaf(hv.x, wv.x, hp[0][0]);
    hp[0][1] = fmaf(hv.x, wv.y, hp[0][1]);
    hp[0][2] = fmaf(hv.x, wv.z, hp[0][2]);
    hp[0][3] = fmaf(hv.x, wv.w, hp[0][3]);
    hp[1][0] = fmaf(hv.y, wv.x, hp[1][0]);
    hp[1][1] = fmaf(hv.y, wv.y, hp[1][1]);
    hp[1][2] = fmaf(hv.y, wv.z, hp[1][2]);
    hp[1][3] = fmaf(hv.y, wv.w, hp[1][3]);
    hp[2][0] = fmaf(hv.z, wv.x, hp[2][0]);
    hp[2][1] = fmaf(hv.z, wv.y, hp[2][1]);
    hp[2][2] = fmaf(hv.z, wv.z, hp[2][2]);
    hp[2][3] = fmaf(hv.z, wv.w, hp[2][3]);
    hp[3][0] = fmaf(hv.w, wv.x, hp[3][0]);
    hp[3][1] = fmaf(hv.w, wv.y, hp[3][1]);
    hp[3][2] = fmaf(hv.w, wv.z, hp[3][2]);
    hp[3][3] = fmaf(hv.w, wv.w, hp[3][3]);
  }

  float as[4], ad[4], f0[4], f1[4];
#pragma unroll
  for (int u = 0; u < 4; ++u) {
    as[u] = a_src[kh * OO + o0 + u];
    ad[u] = a_dst[kh * OO + o0 + u];
    f0[u] = fc_w[0 * (KK * OO) + k * OO + o0 + u];
    f1[u] = fc_w[1 * (KK * OO) + k * OO + o0 + u];
  }

#pragma unroll
  for (int j = 0; j < 4; ++j) {
    float sp = 0.0f, dp = 0.0f, g0 = 0.0f, g1 = 0.0f;
#pragma unroll
    for (int u = 0; u < 4; ++u) {
      float v = hp[j][u];
      float t = ftanh(v);
      sp = fmaf(t, as[u], sp);
      dp = fmaf(t, ad[u], dp);
      g0 = fmaf(v, f0[u], g0);
      g1 = fmaf(v, f1[u], g1);
    }
    part[0][r0 + j][og] = sp;
    part[1][r0 + j][og] = dp;
    part[2][r0 + j][og] = g0;
    part[3][r0 + j][og] = g1;
  }
  __syncthreads();

  {  // thread = (row j2, val): sum 16 og-partials, write out
    const int val = tid & 3;
    const int j2 = tid >> 2;
    const float* pr = &part[val][j2][0];
    vf4 s0 = *(const vf4*)(pr + 0);
    vf4 s1 = *(const vf4*)(pr + 4);
    vf4 s2 = *(const vf4*)(pr + 8);
    vf4 s3 = *(const vf4*)(pr + 12);
    vf4 t4 = s0 + s1 + s2 + s3;
    float sum = t4.x + t4.y + t4.z + t4.w;
    if (val < 2) sum *= LOG2E;
    float* base = (val == 0) ? src_s : (val == 1) ? att_d
                 : (val == 2) ? att_g0 : att_g1;
    base[kh * NN + i0 + j2] = sum;
  }
}

// ---------------------------------------------------------------------------
// Phase 2: partial softmax sums over a 512-j chunk, 16 rows per block.
// grid (NU/16, K*JSPLIT), block 256 = 4 waves. Lane = (jsub<<4) | row.
// Block stages the chunk's att planes (12 x 512 floats = 24 KB) into LDS;
// per 16-j tile: 1 dense global adj b128 (prefetched 4 deep) + 12 broadcast
// ds_read_b128 + packed-f32 VALU on j-pairs (vf2 views of the vf4 data):
//   p = adj * exp2(max(s, 0.2s))  [log2-domain leaky]; l += p; a_c += p*g_c
// Reduction: fold pair + butterfly xor 16,32 + LDS combine across 4 waves.
// ---------------------------------------------------------------------------
__global__ __launch_bounds__(256) void gat_phase2(
    const float* __restrict__ adj, const float* __restrict__ src_s,
    const float* __restrict__ att_d, const float* __restrict__ att_g0,
    const float* __restrict__ att_g1, float* __restrict__ P) {
  const int k = blockIdx.y >> 3;
  const int chunk = blockIdx.y & 7;
  const int r0 = blockIdx.x * 16;
  const int tid = threadIdx.x;
  const int wave = tid >> 6;
  const int lane = tid & 63;
  const int row = lane & 15;
  const int jsub = lane >> 4;
  const int i = r0 + row;
  const int j0 = chunk * JCHUNK;

  vf2 sreg2[4];
#pragma unroll
  for (int h = 0; h < 4; ++h) {
    float s = src_s[(k * HH + h) * NN + i];
    sreg2[h].x = s;
    sreg2[h].y = s;
  }

  // ---- stage att chunk into LDS: lds_att[v][j], v = plane*4 + h ----
  __shared__ float lds_att[12][JCHUNK];
  {
    const float* planes[3] = {att_d, att_g0, att_g1};
#pragma unroll
    for (int step = 0; step < 6; ++step) {  // 1536 vf4 / 256 thr
      const int fi = step * 256 + tid;
      const int v = fi >> 7;  // 128 vf4 per (plane,h) row
      const int pos = (fi & 127) * 4;
      const int p = v >> 2, h = v & 3;
      vf4 val = *(const vf4*)(planes[p] + (size_t)(k * HH + h) * NN + j0 + pos);
      *(vf4*)&lds_att[v][pos] = val;
    }
  }

  vf2 l2[4], a02[4], a12[4];
#pragma unroll
  for (int h = 0; h < 4; ++h) {
    l2[h] = (vf2)(0.0f);
    a02[h] = (vf2)(0.0f);
    a12[h] = (vf2)(0.0f);
  }

  __syncthreads();

  // 32 tiles of 16 j; wave handles t = wave + s*4, s = 0..7. Prefetch 4 deep.
  const float* arow =
      adj + (size_t)k * NN * NN + (size_t)i * NN + j0 + jsub * 4;
  vf4 apre[4];
#pragma unroll
  for (int q = 0; q < 4; ++q)
    apre[q] = *(const vf4*)(arow + (wave + q * 4) * 16);

#pragma unroll
  for (int s = 0; s < 8; ++s) {
    const int t = wave + s * 4;
    const vf4 av = apre[s & 3];
    if (s < 4) apre[s & 3] = *(const vf4*)(arow + (wave + (s + 4) * 4) * 16);
    const int jloc = jsub * 4 + t * 16;
#pragma unroll
    for (int h = 0; h < 4; ++h) {
      vf4 dv = *(const vf4*)&lds_att[0 * 4 + h][jloc];
      vf4 g0v = *(const vf4*)&lds_att[1 * 4 + h][jloc];
      vf4 g1v = *(const vf4*)&lds_att[2 * 4 + h][jloc];
#pragma unroll
      for (int pp = 0; pp < 2; ++pp) {
        vf2 dpair = {dv[2 * pp], dv[2 * pp + 1]};
        vf2 apair = {av[2 * pp], av[2 * pp + 1]};
        vf2 g0p = {g0v[2 * pp], g0v[2 * pp + 1]};
        vf2 g1p = {g1v[2 * pp], g1v[2 * pp + 1]};
        vf2 s2 = sreg2[h] + dpair;                     // v_pk_add_f32
        vf2 sl = __builtin_elementwise_max(s2, s2 * 0.2f);  // pk_mul + pk_max
        vf2 e;
        e.x = fexp2(sl.x);
        e.y = fexp2(sl.y);
        vf2 p2 = apair * e;                            // v_pk_mul_f32
        l2[h] += p2;                                   // v_pk_add_f32
        a02[h] = __builtin_elementwise_fma(p2, g0p, a02[h]);  // v_pk_fma_f32
        a12[h] = __builtin_elementwise_fma(p2, g1p, a12[h]);
      }
    }
  }

  // fold pairs, then butterfly over jsub (lane bits 4,5)
  float l[4], a0[4], a1[4];
#pragma unroll
  for (int h = 0; h < 4; ++h) {
    l[h] = l2[h].x + l2[h].y;
    a0[h] = a02[h].x + a02[h].y;
    a1[h] = a12[h].x + a12[h].y;
    l[h] += __shfl_xor(l[h], 16, 64);
    l[h] += __shfl_xor(l[h], 32, 64);
    a0[h] += __shfl_xor(a0[h], 16, 64);
    a0[h] += __shfl_xor(a0[h], 32, 64);
    a1[h] += __shfl_xor(a1[h], 16, 64);
    a1[h] += __shfl_xor(a1[h], 32, 64);
  }

  // cross-wave combine: sred[wave][v][row], v = h*3+c
  __shared__ float sred[4][12][16];
  if (lane < 16) {
#pragma unroll
    for (int h = 0; h < 4; ++h) {
      sred[wave][h * 3 + 0][row] = l[h];
      sred[wave][h * 3 + 1][row] = a0[h];
      sred[wave][h * 3 + 2][row] = a1[h];
    }
  }
  __syncthreads();
  if (tid < 192) {
    const int v = tid >> 4;  // 0..11 = h*3+c
    const int rr = tid & 15;
    float sum =
        sred[0][v][rr] + sred[1][v][rr] + sred[2][v][rr] + sred[3][v][rr];
    const int h = v / 3, c = v % 3;
    // P layout: [k][chunk][h][{l,a0,a1}][i]
    size_t base =
        ((((size_t)(k * JSPLIT + chunk) * HH + h) * 3 + c)) * NU + (r0 + rr);
    P[base] = sum;
  }
}

// ---------------------------------------------------------------------------
// Phase 3: combine chunk partials, divide, mean heads, sum kinds, +bias,
// log_softmax over C=2.
// ---------------------------------------------------------------------------
__global__ __launch_bounds__(256) void gat_phase3(
    const float* __restrict__ P, const float* __restrict__ fc_b,
    float* __restrict__ out) {
  const int i = blockIdx.x * 256 + threadIdx.x;
  if (i >= NU) return;
  float l0 = fc_b[0], l1 = fc_b[1];
#pragma unroll
  for (int k = 0; k < KK; ++k) {
#pragma unroll
    for (int q = 0; q < HH; ++q) {
      float ls = 0.0f, a0 = 0.0f, a1 = 0.0f;
#pragma unroll
      for (int ch = 0; ch < JSPLIT; ++ch) {
        size_t b = (((size_t)(k * JSPLIT + ch) * HH + q) * 3) * NU + i;
        ls += P[b];
        a0 += P[b + NU];
        a1 += P[b + 2 * (size_t)NU];
      }
      float inv = 1.0f / ls;
      l0 = fmaf(0.25f * a0, inv, l0);
      l1 = fmaf(0.25f * a1, inv, l1);
    }
  }
  float m = fmaxf(l0, l1);
  float lse = m + logf(expf(l0 - m) + expf(l1 - m));
  out[i * CC + 0] = l0 - lse;
  out[i * CC + 1] = l1 - lse;
}

extern "C" void kernel_launch(void* const* d_in, const int* in_sizes, int n_in,
                              void* d_out, int out_size, void* d_ws, size_t ws_size,
                              hipStream_t stream) {
  const float* hsrc  = (const float*)d_in[0];  // (1,4096,64)
  const float* hadj  = (const float*)d_in[1];  // (2,1,4096,4096)
  const float* w     = (const float*)d_in[2];  // (2,4,64,64)
  const float* a_src = (const float*)d_in[3];  // (2,4,64,1)
  const float* a_dst = (const float*)d_in[4];  // (2,4,64,1)
  const float* fc_w  = (const float*)d_in[5];  // (2,128)
  const float* fc_b  = (const float*)d_in[6];  // (2,)
  float* out = (float*)d_out;                  // (1,4000,2) fp32

  char* ws = (char*)d_ws;
  float* src_s  = (float*)(ws + 0 * 131072);   // K*H*N floats (128 KB each)
  float* att_d  = (float*)(ws + 1 * 131072);
  float* att_g0 = (float*)(ws + 2 * 131072);
  float* att_g1 = (float*)(ws + 3 * 131072);
  float* P      = (float*)(ws + 4 * 131072);   // K*JSPLIT*H*3*NU = 3 MB

  dim3 g1(NN / 64, KK * HH);
  gat_phase1<<<g1, 256, 0, stream>>>(hsrc, w, a_src, a_dst, fc_w,
                                     src_s, att_d, att_g0, att_g1);
  dim3 g2(NU / 16, KK * JSPLIT);
  gat_phase2<<<g2, 256, 0, stream>>>(hadj, src_s, att_d, att_g0, att_g1, P);
  gat_phase3<<<(NU + 255) / 256, 256, 0, stream>>>(P, fc_b, out);
}

// Round 9
// 222.027 us; speedup vs baseline: 1.0651x; 1.0147x over previous
//
#include <hip/hip_runtime.h>
#include <math.h>

constexpr int KK = 2;
constexpr int HH = 4;
constexpr int NN = 4096;
constexpr int DD = 64;
constexpr int OO = 64;
constexpr int NU = 4000;
constexpr int CC = 2;
constexpr int JSPLIT = 16;
constexpr int JCHUNK = NN / JSPLIT;  // 256
constexpr float LOG2E = 1.44269504088896340736f;

typedef float vf4 __attribute__((ext_vector_type(4)));
typedef float vf2 __attribute__((ext_vector_type(2)));

__device__ __forceinline__ float fexp2(float x) {
#if __has_builtin(__builtin_amdgcn_exp2f)
  return __builtin_amdgcn_exp2f(x);
#else
  return exp2f(x);
#endif
}
__device__ __forceinline__ float frcp(float x) {
#if __has_builtin(__builtin_amdgcn_rcpf)
  return __builtin_amdgcn_rcpf(x);
#else
  return 1.0f / x;
#endif
}
__device__ __forceinline__ float ftanh(float x) {
  float e = fexp2(x * (2.0f * LOG2E));
  return 1.0f - 2.0f * frcp(e + 1.0f);
}

// ---------------------------------------------------------------------------
// Phase 1: per (k,h): hp = h @ w (4096x64 @ 64x64); per node i:
//   srcAA[kh][i] = {2^src', 2^(0.2 src')}   (src' = (tanh(hp_i).a_src)*log2e)
//   bb5  [kh][j] = {2^dst', 2^(0.2 dst')}
//   gg   [kh][j] = {hp_j.fc_w0, hp_j.fc_w1}
// Factorized leaky-softmax: exp2(max(s,0.2s)) = max(A*B, A5*B5).
// grid (64, K*H), block 256. Thread = 4 rows x 4 o tile; LDS transpose epi.
// ---------------------------------------------------------------------------
__global__ __launch_bounds__(256) void gat_phase1(
    const float* __restrict__ hsrc, const float* __restrict__ w,
    const float* __restrict__ a_src, const float* __restrict__ a_dst,
    const float* __restrict__ fc_w,
    float* __restrict__ srcAA, float* __restrict__ bb5,
    float* __restrict__ gg) {
  const int kh = blockIdx.y;  // 0..7
  const int k = kh >> 2;
  const int i0 = blockIdx.x * 64;
  const int tid = threadIdx.x;

  __shared__ float h_s[DD][68];
  __shared__ float w_s[DD][OO];
  __shared__ float part[4][64][17];  // [val][row][og], padded

  {
    const vf4* wp = (const vf4*)(w + (size_t)kh * DD * OO);
    vf4* ws4 = (vf4*)w_s;
    for (int t = tid; t < DD * OO / 4; t += 256) ws4[t] = wp[t];
  }
  for (int t = tid; t < 1024; t += 256) {
    const int row = t >> 4;
    const int f4 = (t & 15) * 4;
    vf4 v = *(const vf4*)(hsrc + (size_t)(i0 + row) * DD + f4);
    h_s[f4 + 0][row] = v.x;
    h_s[f4 + 1][row] = v.y;
    h_s[f4 + 2][row] = v.z;
    h_s[f4 + 3][row] = v.w;
  }
  __syncthreads();

  const int og = tid & 15;
  const int rg = tid >> 4;
  const int o0 = og * 4;
  const int r0 = rg * 4;

  float hp[4][4];
#pragma unroll
  for (int j = 0; j < 4; ++j)
#pragma unroll
    for (int u = 0; u < 4; ++u) hp[j][u] = 0.0f;

#pragma unroll 8
  for (int f = 0; f < DD; ++f) {
    vf4 hv = *(const vf4*)&h_s[f][r0];
    vf4 wv = *(const vf4*)&w_s[f][o0];
    hp[0][0] = fmaf(hv.x, wv.x, hp[0][0]);
    hp[0][1] = fmaf(hv.x, wv.y, hp[0][1]);
    hp[0][2] = fmaf(hv.x, wv.z, hp[0][2]);
    hp[0][3] = fmaf(hv.x, wv.w, hp[0][3]);
    hp[1][0] = fmaf(hv.y, wv.x, hp[1][0]);
    hp[1][1] = fmaf(hv.y, wv.y, hp[1][1]);
    hp[1][2] = fmaf(hv.y, wv.z, hp[1][2]);
    hp[1][3] = fmaf(hv.y, wv.w, hp[1][3]);
    hp[2][0] = fmaf(hv.z, wv.x, hp[2][0]);
    hp[2][1] = fmaf(hv.z, wv.y, hp[2][1]);
    hp[2][2] = fmaf(hv.z, wv.z, hp[2][2]);
    hp[2][3] = fmaf(hv.z, wv.w, hp[2][3]);
    hp[3][0] = fmaf(hv.w, wv.x, hp[3][0]);
    hp[3][1] = fmaf(hv.w, wv.y, hp[3][1]);
    hp[3][2] = fmaf(hv.w, wv.z, hp[3][2]);
    hp[3][3] = fmaf(hv.w, wv.w, hp[3][3]);
  }

  float as[4], ad[4], f0[4], f1[4];
#pragma unroll
  for (int u = 0; u < 4; ++u) {
    as[u] = a_src[kh * OO + o0 + u];
    ad[u] = a_dst[kh * OO + o0 + u];
    f0[u] = fc_w[0 * (KK * OO) + k * OO + o0 + u];
    f1[u] = fc_w[1 * (KK * OO) + k * OO + o0 + u];
  }

#pragma unroll
  for (int j = 0; j < 4; ++j) {
    float sp = 0.0f, dp = 0.0f, g0 = 0.0f, g1 = 0.0f;
#pragma unroll
    for (int u = 0; u < 4; ++u) {
      float v = hp[j][u];
      float t = ftanh(v);
      sp = fmaf(t, as[u], sp);
      dp = fmaf(t, ad[u], dp);
      g0 = fmaf(v, f0[u], g0);
      g1 = fmaf(v, f1[u], g1);
    }
    part[0][r0 + j][og] = sp;
    part[1][r0 + j][og] = dp;
    part[2][r0 + j][og] = g0;
    part[3][r0 + j][og] = g1;
  }
  __syncthreads();

  {  // thread = (row j2, val): sum 16 og-partials, transform, write out
    const int val = tid & 3;
    const int j2 = tid >> 2;
    const float* pr = &part[val][j2][0];
    vf4 s0 = *(const vf4*)(pr + 0);
    vf4 s1 = *(const vf4*)(pr + 4);
    vf4 s2 = *(const vf4*)(pr + 8);
    vf4 s3 = *(const vf4*)(pr + 12);
    vf4 t4 = s0 + s1 + s2 + s3;
    float sum = t4.x + t4.y + t4.z + t4.w;
    const size_t idx = (size_t)kh * NN + i0 + j2;
    if (val == 0) {
      float sp = sum * LOG2E;
      vf2 v = {fexp2(sp), fexp2(0.2f * sp)};
      *(vf2*)(srcAA + idx * 2) = v;
    } else if (val == 1) {
      float dp = sum * LOG2E;
      vf2 v = {fexp2(dp), fexp2(0.2f * dp)};
      *(vf2*)(bb5 + idx * 2) = v;
    } else {
      gg[idx * 2 + (val - 2)] = sum;
    }
  }
}

// ---------------------------------------------------------------------------
// Phase 2: partial softmax sums over a 256-j chunk, 16 rows per block.
// grid (NU/16, K*JSPLIT), block 256 = 4 waves. Lane = (jsub<<4) | row.
// LDS: (B,B5) and (g0,g1) pairs, 16 KB + 3 KB reduce -> 7-8 blocks/CU.
// Per 16-j tile per wave: 1 dense global adj b128 (all 4 tiles prefetched
// upfront) + 16 broadcast ds_read_b128 + exp-free VALU:
//   e = max(A*B, A5*B5)  [== exp2(leaky(s)), exact identity]
//   pa = adj*e; l += pa; a_c += pa*g_c
// Reduction: butterfly xor 16,32 + LDS combine across 4 waves.
// ---------------------------------------------------------------------------
__global__ __launch_bounds__(256) void gat_phase2(
    const float* __restrict__ adj, const float* __restrict__ srcAA,
    const float* __restrict__ bb5, const float* __restrict__ gg,
    float* __restrict__ P) {
  const int k = blockIdx.y >> 4;
  const int chunk = blockIdx.y & 15;
  const int r0 = blockIdx.x * 16;
  const int tid = threadIdx.x;
  const int wave = tid >> 6;
  const int lane = tid & 63;
  const int row = lane & 15;
  const int jsub = lane >> 4;
  const int i = r0 + row;
  const int j0 = chunk * JCHUNK;

  __shared__ float lds_bb[HH][JCHUNK * 2];
  __shared__ float lds_gg[HH][JCHUNK * 2];

  // stage both pair-planes: 2 arrays x 4 h x 512 floats = 1024 vf4
#pragma unroll
  for (int step = 0; step < 4; ++step) {
    const int idx = step * 256 + tid;
    const int sel = idx >> 9;
    const int h = (idx >> 7) & 3;
    const int pos = (idx & 127) * 4;
    const float* src =
        (sel ? gg : bb5) + ((size_t)(k * HH + h) * NN + j0) * 2 + pos;
    vf4 v = *(const vf4*)src;
    if (sel)
      *(vf4*)&lds_gg[h][pos] = v;
    else
      *(vf4*)&lds_bb[h][pos] = v;
  }

  vf2 AA[4];
#pragma unroll
  for (int h = 0; h < 4; ++h)
    AA[h] = *(const vf2*)(srcAA + ((size_t)(k * HH + h) * NN + i) * 2);

  float l[4], a0[4], a1[4];
#pragma unroll
  for (int h = 0; h < 4; ++h) {
    l[h] = 0.0f;
    a0[h] = 0.0f;
    a1[h] = 0.0f;
  }

  __syncthreads();

  // 16 tiles of 16 j; wave handles t = wave + s*4, s=0..3, all prefetched.
  const float* arow =
      adj + (size_t)k * NN * NN + (size_t)i * NN + j0 + jsub * 4;
  vf4 aj[4];
#pragma unroll
  for (int q = 0; q < 4; ++q)
    aj[q] = *(const vf4*)(arow + (wave + q * 4) * 16);

#pragma unroll
  for (int s = 0; s < 4; ++s) {
    const int t = wave + s * 4;
    const vf4 av = aj[s];
    const int jl = (t * 16 + jsub * 4) * 2;
#pragma unroll
    for (int h = 0; h < 4; ++h) {
      vf4 b01 = *(const vf4*)&lds_bb[h][jl];
      vf4 b23 = *(const vf4*)&lds_bb[h][jl + 4];
      vf4 g01 = *(const vf4*)&lds_gg[h][jl];
      vf4 g23 = *(const vf4*)&lds_gg[h][jl + 4];
      vf2 bp[4] = {{b01.x, b01.y}, {b01.z, b01.w}, {b23.x, b23.y}, {b23.z, b23.w}};
      vf2 gp[4] = {{g01.x, g01.y}, {g01.z, g01.w}, {g23.x, g23.y}, {g23.z, g23.w}};
#pragma unroll
      for (int jj = 0; jj < 4; ++jj) {
        vf2 PP = AA[h] * bp[jj];           // v_pk_mul_f32: {A*B, A5*B5}
        float e = fmaxf(PP.x, PP.y);       // = exp2(leaky(s)), exact
        float pa = e * av[jj];
        l[h] += pa;
        a0[h] = fmaf(pa, gp[jj].x, a0[h]);
        a1[h] = fmaf(pa, gp[jj].y, a1[h]);
      }
    }
  }

  // butterfly over jsub (lane bits 4,5)
#pragma unroll
  for (int h = 0; h < 4; ++h) {
    l[h] += __shfl_xor(l[h], 16, 64);
    l[h] += __shfl_xor(l[h], 32, 64);
    a0[h] += __shfl_xor(a0[h], 16, 64);
    a0[h] += __shfl_xor(a0[h], 32, 64);
    a1[h] += __shfl_xor(a1[h], 16, 64);
    a1[h] += __shfl_xor(a1[h], 32, 64);
  }

  // cross-wave combine: sred[wave][v][row], v = h*3+c
  __shared__ float sred[4][12][16];
  if (lane < 16) {
#pragma unroll
    for (int h = 0; h < 4; ++h) {
      sred[wave][h * 3 + 0][row] = l[h];
      sred[wave][h * 3 + 1][row] = a0[h];
      sred[wave][h * 3 + 2][row] = a1[h];
    }
  }
  __syncthreads();
  if (tid < 192) {
    const int v = tid >> 4;  // 0..11 = h*3+c
    const int rr = tid & 15;
    float sum =
        sred[0][v][rr] + sred[1][v][rr] + sred[2][v][rr] + sred[3][v][rr];
    const int h = v / 3, c = v % 3;
    // P layout: [k][chunk][h][{l,a0,a1}][i]
    size_t base =
        ((((size_t)(k * JSPLIT + chunk) * HH + h) * 3 + c)) * NU + (r0 + rr);
    P[base] = sum;
  }
}

// ---------------------------------------------------------------------------
// Phase 3: combine chunk partials, divide, mean heads, sum kinds, +bias,
// log_softmax over C=2.
// ---------------------------------------------------------------------------
__global__ __launch_bounds__(256) void gat_phase3(
    const float* __restrict__ P, const float* __restrict__ fc_b,
    float* __restrict__ out) {
  const int i = blockIdx.x * 256 + threadIdx.x;
  if (i >= NU) return;
  float l0 = fc_b[0], l1 = fc_b[1];
#pragma unroll
  for (int k = 0; k < KK; ++k) {
#pragma unroll
    for (int q = 0; q < HH; ++q) {
      float ls = 0.0f, a0 = 0.0f, a1 = 0.0f;
#pragma unroll
      for (int ch = 0; ch < JSPLIT; ++ch) {
        size_t b = (((size_t)(k * JSPLIT + ch) * HH + q) * 3) * NU + i;
        ls += P[b];
        a0 += P[b + NU];
        a1 += P[b + 2 * (size_t)NU];
      }
      float inv = 1.0f / ls;
      l0 = fmaf(0.25f * a0, inv, l0);
      l1 = fmaf(0.25f * a1, inv, l1);
    }
  }
  float m = fmaxf(l0, l1);
  float lse = m + logf(expf(l0 - m) + expf(l1 - m));
  out[i * CC + 0] = l0 - lse;
  out[i * CC + 1] = l1 - lse;
}

extern "C" void kernel_launch(void* const* d_in, const int* in_sizes, int n_in,
                              void* d_out, int out_size, void* d_ws, size_t ws_size,
                              hipStream_t stream) {
  const float* hsrc  = (const float*)d_in[0];  // (1,4096,64)
  const float* hadj  = (const float*)d_in[1];  // (2,1,4096,4096)
  const float* w     = (const float*)d_in[2];  // (2,4,64,64)
  const float* a_src = (const float*)d_in[3];  // (2,4,64,1)
  const float* a_dst = (const float*)d_in[4];  // (2,4,64,1)
  const float* fc_w  = (const float*)d_in[5];  // (2,128)
  const float* fc_b  = (const float*)d_in[6];  // (2,)
  float* out = (float*)d_out;                  // (1,4000,2) fp32

  char* ws = (char*)d_ws;
  float* srcAA = (float*)(ws + 0);        // K*H*N float2  (256 KB)
  float* bb5   = (float*)(ws + 262144);   // K*H*N float2  (256 KB)
  float* gg    = (float*)(ws + 524288);   // K*H*N float2  (256 KB)
  float* P     = (float*)(ws + 786432);   // K*JSPLIT*H*3*NU floats (~6.1 MB)

  dim3 g1(NN / 64, KK * HH);
  gat_phase1<<<g1, 256, 0, stream>>>(hsrc, w, a_src, a_dst, fc_w,
                                     srcAA, bb5, gg);
  dim3 g2(NU / 16, KK * JSPLIT);
  gat_phase2<<<g2, 256, 0, stream>>>(hadj, srcAA, bb5, gg, P);
  gat_phase3<<<(NU + 255) / 256, 256, 0, stream>>>(P, fc_b, out);
}